// Round 7
// baseline (121.076 us; speedup 1.0000x reference)
//
#include <hip/hip_runtime.h>

#define IN_DIM  4096
#define OUT_DIM 11008
#define NSUB    1376
#define KSQ     256
#define DSUB    8
#define BATCH   32

#define KSPLIT  16
#define KPB     (IN_DIM / KSPLIT)    // 256 k per block
#define NSTEP   (KPB / 32)           // 8 k-steps
#define NBLK    (OUT_DIM / 64)       // 172 (block = 4 waves x 16 cols)

typedef unsigned short ushort_t;
typedef unsigned int   uint_t;
typedef unsigned char  u8;
typedef __attribute__((ext_vector_type(8))) short bf16x8;
typedef __attribute__((ext_vector_type(4))) float f32x4;

// workspace layout (bytes)
#define VEC_N    (NSUB * KSQ * DSUB)              // 2818048 floats
#define XBF_OFF  (VEC_N * 2)                      // 5636096
#define IDX_OFF  (XBF_OFF + BATCH * IN_DIM * 2)   // 5898240
#define PART_OFF (IDX_OFF + NSUB * IN_DIM)        // 11534336
#define PREP_V   (VEC_N / 2)                      // 1409024
#define PREP_X   (BATCH * IN_DIM / 2)             // 65536
#define PREP_N   (PREP_V + PREP_X)                // 1474560 = 5760 * 256
#define PREP_B   (PREP_N / 256)                   // 5760
#define TR_B     ((IN_DIM / 256) * (NSUB / 32))   // 688

__device__ __forceinline__ ushort_t f2bf(float f) {
    union { float f; uint_t u; } a; a.f = f;
    uint_t u = a.u;
    u += 0x7fffu + ((u >> 16) & 1u);   // round-to-nearest-even
    return (ushort_t)(u >> 16);
}

// async global -> LDS, 16B per lane; lptr must be wave-uniform base
__device__ __forceinline__ void gl2lds16(const void* g, void* l) {
    __builtin_amdgcn_global_load_lds(
        (const __attribute__((address_space(1))) void*)g,
        (__attribute__((address_space(3))) void*)l, 16, 0, 0);
}

// Fused: bf16-cast of vectors & x, and idx int32 -> u8 transpose.
__global__ __launch_bounds__(256) void pq_prep(
    const float* __restrict__ x, const float* __restrict__ vecs,
    const int* __restrict__ idx,
    uint_t* __restrict__ vbf, uint_t* __restrict__ xbf, u8* __restrict__ idxT)
{
    __shared__ u8 sT[32 * 260];
    const int bx = blockIdx.x;
    if (bx < PREP_B) {
        int tid = bx * 256 + threadIdx.x;
        if (tid < PREP_V) {
            float2 v = ((const float2*)vecs)[tid];
            vbf[tid] = (uint_t)f2bf(v.x) | ((uint_t)f2bf(v.y) << 16);
        } else {
            int i = tid - PREP_V;
            float2 v = ((const float2*)x)[i];
            xbf[i] = (uint_t)f2bf(v.x) | ((uint_t)f2bf(v.y) << 16);
        }
    } else {
        // transpose tile: 32 d x 256 i
        const int b2  = bx - PREP_B;
        const int i0  = (b2 & 15) * 256;
        const int d0t = (b2 >> 4) * 32;
        const int dd = threadIdx.x & 31;
        const int ib = threadIdx.x >> 5;
        #pragma unroll 8
        for (int ii = 0; ii < 32; ++ii) {
            int il = ii * 8 + ib;
            sT[dd * 260 + il] = (u8)idx[(size_t)(i0 + il) * NSUB + d0t + dd];
        }
        __syncthreads();
        const int l  = threadIdx.x & 63;
        const int w4 = threadIdx.x >> 6;
        #pragma unroll
        for (int rr = 0; rr < 8; ++rr) {
            int row = rr * 4 + w4;
            uint_t v = *(const uint_t*)&sT[row * 260 + l * 4];
            *(uint_t*)&idxT[(size_t)(d0t + row) * IN_DIM + i0 + l * 4] = v;
        }
    }
}

// VMEM-free inner loop: all global traffic in the prologue (codes + A-frags
// into registers, codebook into LDS via global_load_lds). Inner loop is
// LDS gather + diagonal-scratch transpose + MFMA only.
__global__ __launch_bounds__(256, 4) void pq_main(
    const ushort_t* __restrict__ xbf, const uint4* __restrict__ vbf,
    const u8* __restrict__ idxT, float* __restrict__ part)
{
    __shared__ uint4 sCB[8 * KSQ];     // 32 KB: block's 8 bf16 sub-codebooks
    __shared__ uint4 sScr[2][4][64];   // 8 KB: transpose scratch

    const int t    = threadIdx.x;
    const int wave = t >> 6;
    const int lane = t & 63;
    const int n    = lane & 15;
    const int oct  = lane >> 4;
    const int jn   = n & 7;
    const int dloc = n >> 3;
    const int grp  = lane >> 3;
    const int w    = jn >> 1;
    const uint_t sel = (jn & 1) ? 0x07060302u : 0x05040100u;

    const int nblk  = blockIdx.x;      // 0..171
    const int kblk  = blockIdx.y;      // 0..15
    const int kbase = kblk * KPB;
    const int dl    = wave * 2 + dloc;           // lane's d within block
    const int d     = nblk * 8 + dl;

    // --- prologue: issue ALL global traffic, then one barrier ---
    // (1) codebook -> LDS, coalesced, zero VGPR round-trip
    {
        const uint4* vb4 = vbf + (size_t)(nblk * 8) * KSQ;
        const int wb = wave * 64;                // wave-uniform LDS base
        #pragma unroll
        for (int p = 0; p < 8; ++p)
            gl2lds16(vb4 + p * 256 + t, &sCB[p * 256 + wb]);
    }
    // (2) this lane's 8 step-codes
    const u8* ip = idxT + (size_t)d * IN_DIM + kbase + oct * 8 + jn;
    uint_t code[NSTEP];
    #pragma unroll
    for (int s = 0; s < NSTEP; ++s) code[s] = ip[s * 32];
    // (3) A fragments for all 8 steps into registers (reused, no reload)
    const ushort_t* xr = xbf + kbase + oct * 8;
    bf16x8 A0[NSTEP], A1[NSTEP];
    #pragma unroll
    for (int s = 0; s < NSTEP; ++s)
        A0[s] = *(const bf16x8*)(xr + (size_t)n * IN_DIM + s * 32);
    #pragma unroll
    for (int s = 0; s < NSTEP; ++s)
        A1[s] = *(const bf16x8*)(xr + (size_t)(16 + n) * IN_DIM + s * 32);

    __syncthreads();   // drains vmcnt (codebook landed) + lgkm

    // --- scratch addressing (R6-verified diagonal permutation) ---
    const int slot = grp * 8 + ((jn + grp) & 7);
    uint4* wr[2] = { &sScr[0][wave][slot], &sScr[1][wave][slot] };
    const uint_t* rb[2] = { (const uint_t*)&sScr[0][wave][grp * 8],
                            (const uint_t*)&sScr[1][wave][grp * 8] };

    f32x4 acc0 = (f32x4)0.0f, acc1 = (f32x4)0.0f;

    uint4 qcur = sCB[dl * KSQ + code[0]];
    #pragma unroll
    for (int s = 0; s < NSTEP; ++s) {
        const int p = s & 1;
        uint4 qnext;
        if (s + 1 < NSTEP) qnext = sCB[dl * KSQ + code[s + 1]];

        *wr[p] = qcur;                              // ds_write_b128, no conflict
        const uint_t* r = rb[p];
        uint_t r0 = r[((0 + grp) & 7) * 4 + w];
        uint_t r1 = r[((1 + grp) & 7) * 4 + w];
        uint_t r2 = r[((2 + grp) & 7) * 4 + w];
        uint_t r3 = r[((3 + grp) & 7) * 4 + w];
        uint_t r4 = r[((4 + grp) & 7) * 4 + w];
        uint_t r5 = r[((5 + grp) & 7) * 4 + w];
        uint_t r6 = r[((6 + grp) & 7) * 4 + w];
        uint_t r7 = r[((7 + grp) & 7) * 4 + w];

        union { uint_t u[4]; bf16x8 v; } B;
        B.u[0] = __builtin_amdgcn_perm(r1, r0, sel);
        B.u[1] = __builtin_amdgcn_perm(r3, r2, sel);
        B.u[2] = __builtin_amdgcn_perm(r5, r4, sel);
        B.u[3] = __builtin_amdgcn_perm(r7, r6, sel);

        acc0 = __builtin_amdgcn_mfma_f32_16x16x32_bf16(A0[s], B.v, acc0, 0, 0, 0);
        acc1 = __builtin_amdgcn_mfma_f32_16x16x32_bf16(A1[s], B.v, acc1, 0, 0, 0);
        qcur = qnext;
    }

    // --- epilogue: plain stores to split-K partials ---
    float* pp = part + (size_t)kblk * (BATCH * OUT_DIM);
    const int col = nblk * 64 + wave * 16 + n;
    #pragma unroll
    for (int r = 0; r < 4; ++r) {
        int row = oct * 4 + r;
        pp[(size_t)row * OUT_DIM + col] = acc0[r];
        pp[(size_t)(16 + row) * OUT_DIM + col] = acc1[r];
    }
}

__global__ __launch_bounds__(256) void pq_reduce(
    const float* __restrict__ part, const float* __restrict__ bias,
    float* __restrict__ out)
{
    const int bx  = blockIdx.x;              // 1376 = 32 rows * 43 col-blocks
    const int row = bx / 43;
    const int cb  = bx - row * 43;
    const int col = cb * 256 + threadIdx.x;
    const size_t e = (size_t)row * OUT_DIM + col;
    float s = bias[col];
    #pragma unroll
    for (int k = 0; k < KSPLIT; ++k)
        s += part[(size_t)k * (BATCH * OUT_DIM) + e];
    out[e] = s;
}

extern "C" void kernel_launch(void* const* d_in, const int* in_sizes, int n_in,
                              void* d_out, int out_size, void* d_ws, size_t ws_size,
                              hipStream_t stream) {
    const float* x    = (const float*)d_in[0];
    const float* vecs = (const float*)d_in[1];
    const float* bias = (const float*)d_in[2];
    const int*   idx  = (const int*)d_in[3];
    float* out = (float*)d_out;

    uint_t* vbf   = (uint_t*)d_ws;                       // 5.6 MB bf16 codebook
    uint_t* xbf   = (uint_t*)((char*)d_ws + XBF_OFF);    // 256 KB bf16 x
    u8*     idxT8 = (u8*)((char*)d_ws + IDX_OFF);        // 5.6 MB u8 idx^T
    float*  part  = (float*)((char*)d_ws + PART_OFF);    // 22.5 MB fp32 partials

    pq_prep<<<PREP_B + TR_B, 256, 0, stream>>>(x, vecs, idx, vbf, xbf, idxT8);
    dim3 grid(NBLK, KSPLIT);
    pq_main<<<grid, 256, 0, stream>>>((const ushort_t*)xbf, (const uint4*)vbf,
                                      idxT8, part);
    pq_reduce<<<BATCH * OUT_DIM / 256, 256, 0, stream>>>(part, bias, out);
}